// Round 12
// baseline (540.143 us; speedup 1.0000x reference)
//
#include <hip/hip_runtime.h>

#define DN 128
#define SLOTS 64
#define RSZ 512      // nodes per range (power of 2)
#define NCHUNK 512   // edge chunks; dense staged output makes chunk size write-neutral
#define LDSE 3200    // LDS staging capacity >= CE = E/NCHUNK = 3125

typedef __attribute__((ext_vector_type(8))) short bf16x8;
typedef __attribute__((ext_vector_type(4))) float f32x4;
typedef __attribute__((ext_vector_type(2))) float f32x2;

__device__ __forceinline__ unsigned short f2bf(float f) {
  unsigned int b = __float_as_uint(f);
  b += 0x7fffu + ((b >> 16) & 1u);
  return (unsigned short)(b >> 16);
}

__device__ __forceinline__ unsigned int pkmul(unsigned int a, unsigned int b) {
  float a0 = __uint_as_float(a << 16);
  float a1 = __uint_as_float(a & 0xffff0000u);
  float b0 = __uint_as_float(b << 16);
  float b1 = __uint_as_float(b & 0xffff0000u);
  return (unsigned int)f2bf(a0 * b0) | ((unsigned int)f2bf(a1 * b1) << 16);
}

// ---------------- fp8 (OCP e4m3fn) helpers ----------------
// AGGREGATION-ONLY: fp8 on the predictor's pair product measured absmax
// 1.55e-6 > 5.8e-7 threshold (r7) — two fp8 operands multiply, no averaging.
#if __has_builtin(__builtin_amdgcn_cvt_pk_f32_fp8)
template <bool HI>
__device__ __forceinline__ f32x2 fp8pair(unsigned int w) {
  return __builtin_amdgcn_cvt_pk_f32_fp8((int)w, HI);
}
#else
__device__ __forceinline__ float fp8dec1(unsigned int b) {
  float v = __uint_as_float((b & 0x7fu) << 20) * 1.329227996e36f;  // *2^120
  return (b & 0x80u) ? -v : v;
}
template <bool HI>
__device__ __forceinline__ f32x2 fp8pair(unsigned int w) {
  unsigned int s = HI ? (w >> 16) : w;
  f32x2 r;
  r.x = fp8dec1(s & 0xffu);
  r.y = fp8dec1((s >> 8) & 0xffu);
  return r;
}
#endif

#if __has_builtin(__builtin_amdgcn_cvt_pk_fp8_f32)
__device__ __forceinline__ unsigned int f4fp8(float a, float b, float c, float d) {
  int lo = __builtin_amdgcn_cvt_pk_fp8_f32(a, b, 0, false);
  return (unsigned int)__builtin_amdgcn_cvt_pk_fp8_f32(c, d, lo, true);
}
__device__ __forceinline__ unsigned char f1fp8(float v) {
  return (unsigned char)(__builtin_amdgcn_cvt_pk_fp8_f32(v, v, 0, false) & 0xff);
}
#else
__device__ __forceinline__ unsigned char f1fp8(float v) {
  unsigned int sign = (__float_as_uint(v) >> 24) & 0x80u;
  float av = fabsf(v);
  if (av > 448.f) av = 448.f;
  unsigned int byte;
  unsigned int u = __float_as_uint(av);
  if (av < 0.015625f) {  // below min normal 2^-6: subnormal m*2^-9
    int m = (int)(av * 512.0f + 0.5f);
    byte = (unsigned int)m;
  } else {
    u += (1u << 19);
    int ee = (int)(u >> 23) - 127 + 7;
    unsigned int m3 = (u >> 20) & 7;
    if (ee > 15) byte = 0x7eu;
    else byte = ((unsigned int)ee << 3) | m3;
  }
  return (unsigned char)(byte | sign);
}
__device__ __forceinline__ unsigned int f4fp8(float a, float b, float c, float d) {
  return (unsigned int)f1fp8(a) | ((unsigned int)f1fp8(b) << 8) |
         ((unsigned int)f1fp8(c) << 16) | ((unsigned int)f1fp8(d) << 24);
}
#endif

// ---------------- phase A: LDS-staged edge routing + fused emb gather --------
// Two-pass counting sort per chunk -> dense full-line flush (r9: -20us).
// xf8 is written SLICE-MAJOR [8][N][16B] for the XCD-pinned aggregate.
__global__ __launch_bounds__(256) void k_route(const int* __restrict__ snd,
                                               const int* __restrict__ rcv,
                                               int* __restrict__ rbuf,
                                               unsigned short* __restrict__ sbuf,
                                               int* __restrict__ rc, int* __restrict__ ro,
                                               int* __restrict__ sc, int* __restrict__ so,
                                               int E, int CE, int NR,
                                               const int* __restrict__ node_ids,
                                               const float* __restrict__ emb,
                                               unsigned short* __restrict__ x,
                                               unsigned char* __restrict__ xf8, int n) {
  if ((int)blockIdx.x < NCHUNK) {
    __shared__ int cR[256], cS[256], curR[256], curS[256];
    __shared__ int rdata[LDSE];
    __shared__ unsigned short sdata[LDSE];
    int t = threadIdx.x;
    int chunk = blockIdx.x;
    cR[t] = 0;
    cS[t] = 0;
    __syncthreads();
    int e0 = chunk * CE;
    int e1 = e0 + CE;
    if (e1 > E) e1 = E;
    // pass 1: per-range counts (snd/rcv stay L2-hot for pass 2)
    for (int e = e0 + t; e < e1; e += 256) {
      atomicAdd(&cR[rcv[e] >> 9], 1);
      atomicAdd(&cS[snd[e] >> 9], 1);
    }
    __syncthreads();
    // inclusive Hillis-Steele scan -> exclusive cursors
    curR[t] = cR[t];
    curS[t] = cS[t];
    __syncthreads();
#pragma unroll
    for (int off = 1; off < 256; off <<= 1) {
      int aR = (t >= off) ? curR[t - off] : 0;
      int aS = (t >= off) ? curS[t - off] : 0;
      __syncthreads();
      curR[t] += aR;
      curS[t] += aS;
      __syncthreads();
    }
    curR[t] -= cR[t];  // own element only: no cross-thread hazard
    curS[t] -= cS[t];
    __syncthreads();
    // pass 2: scatter into dense LDS staging
    for (int e = e0 + t; e < e1; e += 256) {
      int s = snd[e], r = rcv[e];
      int pos = atomicAdd(&curR[r >> 9], 1);
      rdata[pos] = ((r & (RSZ - 1)) << 17) | s;
      int pos2 = atomicAdd(&curS[s >> 9], 1);
      sdata[pos2] = (unsigned short)(s & (RSZ - 1));
    }
    __syncthreads();
    // flush: dense, coalesced, full-line writes
    int cnt = e1 - e0;
    for (int i = t; i < cnt; i += 256) rbuf[(size_t)chunk * CE + i] = rdata[i];
    for (int i = t; i < cnt; i += 256) sbuf[(size_t)chunk * CE + i] = sdata[i];
    if (t < NR) {
      rc[t * NCHUNK + chunk] = cR[t];
      ro[t * NCHUNK + chunk] = curR[t] - cR[t];  // cursor advanced by exactly cR[t]
      sc[t * NCHUNK + chunk] = cS[t];
      so[t * NCHUNK + chunk] = curS[t] - cS[t];
    }
  } else {
    int gblk = blockIdx.x - NCHUNK;
    int total = n * (DN / 4);
#pragma unroll
    for (int kk = 0; kk < 4; ++kk) {
      int idx = gblk * 1024 + kk * 256 + threadIdx.x;
      if (idx >= total) continue;
      int row = idx >> 5;
      int c4 = (idx & 31) << 2;
      int src = node_ids[row];
      float4 v = *(const float4*)(emb + (size_t)src * DN + c4);
      uint2 o;
      o.x = (unsigned int)f2bf(v.x) | ((unsigned int)f2bf(v.y) << 16);
      o.y = (unsigned int)f2bf(v.z) | ((unsigned int)f2bf(v.w) << 16);
      *(uint2*)(x + (size_t)row * DN + c4) = o;
      // slice-major fp8: slice = c4>>4, inner = c4&15
      *(unsigned int*)(xf8 + ((size_t)(c4 >> 4) * n + row) * 16 + (c4 & 15)) =
          f4fp8(v.x * 256.f, v.y * 256.f, v.z * 256.f, v.w * 256.f);
    }
  }
}

// ---------------- phase B: per-range CSR + degrees + scales (LDS atomics) -----
// Thread t consumes chunks {t, t+256}; segments located via dense offset tables.
__global__ __launch_bounds__(256) void k_build2(const int* __restrict__ rbuf,
                                                const unsigned short* __restrict__ sbuf,
                                                const int* __restrict__ rc,
                                                const int* __restrict__ ro,
                                                const int* __restrict__ sc,
                                                const int* __restrict__ so,
                                                int* __restrict__ cnt_r,
                                                int* __restrict__ csr,
                                                float* __restrict__ scale_s,
                                                float* __restrict__ scale_r,
                                                int N, int CE) {
  __shared__ int cur[RSZ], hist[RSZ];
  int g = blockIdx.x, t = threadIdx.x;
  cur[t] = 0;
  cur[t + 256] = 0;
  hist[t] = 0;
  hist[t + 256] = 0;
  __syncthreads();
#pragma unroll
  for (int cc = 0; cc < 2; ++cc) {
    int chunk = t + cc * 256;
    int cnt = rc[g * NCHUNK + chunk];
    const int* row = rbuf + (size_t)chunk * CE + ro[g * NCHUNK + chunk];
    for (int i = 0; i < cnt; ++i) {
      int e = row[i];
      int rl = e >> 17;
      int s = e & 0x1FFFF;
      int sl = atomicAdd(&cur[rl], 1);
      if (sl < SLOTS) csr[((size_t)g * RSZ + rl) * SLOTS + sl] = s;
    }
    int cnt2 = sc[g * NCHUNK + chunk];
    const unsigned short* row2 = sbuf + (size_t)chunk * CE + so[g * NCHUNK + chunk];
    for (int i = 0; i < cnt2; ++i) atomicAdd(&hist[row2[i]], 1);
  }
  __syncthreads();
#pragma unroll
  for (int k = 0; k < 2; ++k) {
    int tt = t + k * 256;
    int node = g * RSZ + tt;
    if (node < N) {
      int c = cur[tt];
      cnt_r[node] = c;
      float cr = (float)(c + 1);
      scale_r[node] = 1.0f / (cr * sqrtf(cr));
      float ds = (float)(hist[tt] + 1);
      scale_s[node] = 1.0f / sqrtf(ds);
    }
  }
}

// ---------------- weight transpose+convert (all three weights) ----------------
// Wat is emitted in MFMA B-fragment order for k_pred's conflict-free LDS reads.
// (r10: reading Wat from global costs +24us — it must be LDS-staged.)
__global__ __launch_bounds__(256) void k_wt3(const float* __restrict__ W1,
                                             const float* __restrict__ W2,
                                             const float* __restrict__ Wa,
                                             unsigned short* __restrict__ Wt1,
                                             unsigned short* __restrict__ Wt2,
                                             unsigned short* __restrict__ Wat) {
  int idx = blockIdx.x * 256 + threadIdx.x;
  if (idx < 32768) {
    int k = idx >> 7, n = idx & 127;
    Wt1[n * 256 + k] = f2bf(W1[idx]);
  } else if (idx < 65536) {
    int i = idx - 32768;
    int k = i >> 7, n = i & 127;
    Wt2[n * 256 + k] = f2bf(W2[i]);
  } else if (idx < 81920) {
    int i = idx - 65536;
    int k = i >> 7, n = i & 127;
    int ch = k >> 5, quad = (k >> 3) & 3, j = k & 7;
    int nt = n >> 4, lm = n & 15;
    int pos = (((ch * 8 + nt) * 64) + quad * 16 + lm) * 8 + j;
    Wat[pos] = f2bf(Wa[i]);
  }
}

// ---------------- per-node gather aggregation: XCD-pinned K-slices ------------
// xf8s layout [8][N][16B]; block's slice ks = blockIdx%8 == its XCD under the
// empirical round-robin mapping -> each XCD's 1.6MB slice table is L2-resident
// and the 1.6M random edge-gathers become L2 HITS (the r11 line-rate model).
// 4 lanes per node (16B slice), 64 nodes per 256-thread block, zero LDS.
__device__ __forceinline__ void acc8(unsigned int u, float wgt, float& ax, float& ay,
                                     float& az, float& aw) {
  f32x2 lo = fp8pair<false>(u);
  f32x2 hi = fp8pair<true>(u);
  ax += lo.x * wgt;
  ay += lo.y * wgt;
  az += hi.x * wgt;
  aw += hi.y * wgt;
}

__global__ __launch_bounds__(256) void k_aggregate8(const unsigned char* __restrict__ xf8s,
                                                    const int* __restrict__ cnt_r,
                                                    const int* __restrict__ csr,
                                                    const float* __restrict__ scale_s,
                                                    const float* __restrict__ scale_r,
                                                    unsigned short* __restrict__ out, int n) {
  int ks = blockIdx.x & 7;        // K-slice == XCD (blockIdx % 8 round-robin)
  int grp = blockIdx.x >> 3;
  int t = threadIdx.x;
  int node = grp * 64 + (t >> 2);
  if (node >= n) return;
  int lane = t & 3;
  const unsigned char* tbl = xf8s + (size_t)ks * n * 16;
  int start = node * SLOTS;
  int cnt = cnt_r[node];
  if (cnt > SLOTS) cnt = SLOTS;
  int c = lane * 4;  // 4 dims = 4 bytes within the 16B slice
  float ws = scale_s[node];
  float ax = 0.f, ay = 0.f, az = 0.f, aw = 0.f;
  acc8(*(const unsigned int*)(tbl + (size_t)node * 16 + c), ws, ax, ay, az, aw);  // self
  int j = 0;
  for (; j + 8 <= cnt; j += 8) {
    int4 ea = *(const int4*)(csr + start + j);
    int4 eb = *(const int4*)(csr + start + j + 4);
    float w0 = scale_s[ea.x], w1 = scale_s[ea.y], w2 = scale_s[ea.z], w3 = scale_s[ea.w];
    float w4 = scale_s[eb.x], w5 = scale_s[eb.y], w6 = scale_s[eb.z], w7 = scale_s[eb.w];
    unsigned int u0 = *(const unsigned int*)(tbl + (size_t)ea.x * 16 + c);
    unsigned int u1 = *(const unsigned int*)(tbl + (size_t)ea.y * 16 + c);
    unsigned int u2 = *(const unsigned int*)(tbl + (size_t)ea.z * 16 + c);
    unsigned int u3 = *(const unsigned int*)(tbl + (size_t)ea.w * 16 + c);
    unsigned int u4 = *(const unsigned int*)(tbl + (size_t)eb.x * 16 + c);
    unsigned int u5 = *(const unsigned int*)(tbl + (size_t)eb.y * 16 + c);
    unsigned int u6 = *(const unsigned int*)(tbl + (size_t)eb.z * 16 + c);
    unsigned int u7 = *(const unsigned int*)(tbl + (size_t)eb.w * 16 + c);
    acc8(u0, w0, ax, ay, az, aw);
    acc8(u1, w1, ax, ay, az, aw);
    acc8(u2, w2, ax, ay, az, aw);
    acc8(u3, w3, ax, ay, az, aw);
    acc8(u4, w4, ax, ay, az, aw);
    acc8(u5, w5, ax, ay, az, aw);
    acc8(u6, w6, ax, ay, az, aw);
    acc8(u7, w7, ax, ay, az, aw);
  }
  for (; j + 4 <= cnt; j += 4) {
    int4 ea = *(const int4*)(csr + start + j);
    float w0 = scale_s[ea.x], w1 = scale_s[ea.y], w2 = scale_s[ea.z], w3 = scale_s[ea.w];
    unsigned int u0 = *(const unsigned int*)(tbl + (size_t)ea.x * 16 + c);
    unsigned int u1 = *(const unsigned int*)(tbl + (size_t)ea.y * 16 + c);
    unsigned int u2 = *(const unsigned int*)(tbl + (size_t)ea.z * 16 + c);
    unsigned int u3 = *(const unsigned int*)(tbl + (size_t)ea.w * 16 + c);
    acc8(u0, w0, ax, ay, az, aw);
    acc8(u1, w1, ax, ay, az, aw);
    acc8(u2, w2, ax, ay, az, aw);
    acc8(u3, w3, ax, ay, az, aw);
  }
  for (; j < cnt; ++j) {
    int s0 = csr[start + j];
    float w0 = scale_s[s0];
    unsigned int u0 = *(const unsigned int*)(tbl + (size_t)s0 * 16 + c);
    acc8(u0, w0, ax, ay, az, aw);
  }
  float sr = scale_r[node] * 0.00390625f;  // fold 2^-8 dequant scale
  uint2 o;
  o.x = (unsigned int)f2bf(ax * sr) | ((unsigned int)f2bf(ay * sr) << 16);
  o.y = (unsigned int)f2bf(az * sr) | ((unsigned int)f2bf(aw * sr) << 16);
  *(uint2*)(out + (size_t)node * DN + ks * 16 + c) = o;
}

// ---------------- layer GEMM (MFMA bf16): C = relu?( [A1|A2] @ W + bias ) -------
// C (bf16) and Cf8 (fp8 of C*256, SLICE-MAJOR [8][N][16B]) are each optional.
__global__ __launch_bounds__(256) void k_gemm(const unsigned short* __restrict__ A1,
                                              const unsigned short* __restrict__ A2,
                                              const unsigned short* __restrict__ Wt,  // [128][256] bf16
                                              const float* __restrict__ bias,
                                              unsigned short* __restrict__ C,
                                              unsigned char* __restrict__ Cf8,
                                              int nrows, int dorelu) {
  __shared__ unsigned short a_sh[128 * 40];  // [row][k], stride 40 (pad)
  __shared__ unsigned short b_sh[128 * 40];  // [n][k], stride 40
  int t = threadIdx.x;
  int w = t >> 6, l = t & 63, quad = l >> 4, lm = l & 15;
  int row0 = blockIdx.x * 128;
  f32x4 acc[2][8];
#pragma unroll
  for (int i = 0; i < 2; ++i)
#pragma unroll
    for (int j = 0; j < 8; ++j) acc[i][j] = (f32x4){0.f, 0.f, 0.f, 0.f};

  for (int ch = 0; ch < 8; ++ch) {
    const unsigned short* src = (ch < 4) ? A1 : A2;
    int kb = (ch & 3) * 32;
    int kk = ch * 32;
#pragma unroll
    for (int rep = 0; rep < 2; ++rep) {
      int idx = t + rep * 256;
      int r = idx >> 2, q = idx & 3;
      int gr = row0 + r;
      if (gr > nrows - 1) gr = nrows - 1;
      *(uint4*)&a_sh[r * 40 + q * 8] = *(const uint4*)(src + (size_t)gr * DN + kb + q * 8);
      int nn = idx >> 2;
      *(uint4*)&b_sh[nn * 40 + q * 8] = *(const uint4*)(Wt + (size_t)nn * 256 + kk + q * 8);
    }
    __syncthreads();
    bf16x8 af0 = *(bf16x8*)&a_sh[(w * 32 + lm) * 40 + quad * 8];
    bf16x8 af1 = *(bf16x8*)&a_sh[(w * 32 + 16 + lm) * 40 + quad * 8];
#pragma unroll
    for (int nt = 0; nt < 8; ++nt) {
      bf16x8 bfr = *(bf16x8*)&b_sh[(nt * 16 + lm) * 40 + quad * 8];
      acc[0][nt] = __builtin_amdgcn_mfma_f32_16x16x32_bf16(af0, bfr, acc[0][nt], 0, 0, 0);
      acc[1][nt] = __builtin_amdgcn_mfma_f32_16x16x32_bf16(af1, bfr, acc[1][nt], 0, 0, 0);
    }
    __syncthreads();
  }
#pragma unroll
  for (int nt = 0; nt < 8; ++nt) {
    int col = nt * 16 + lm;
    float bv = bias[col];
#pragma unroll
    for (int mt = 0; mt < 2; ++mt)
#pragma unroll
      for (int r = 0; r < 4; ++r) {
        int gr = row0 + w * 32 + mt * 16 + quad * 4 + r;
        if (gr < nrows) {
          float v = acc[mt][nt][r] + bv;
          if (dorelu) v = fmaxf(v, 0.f);
          if (C) C[(size_t)gr * DN + col] = f2bf(v);
          // slice-major: slice == nt, inner == lm (16 lm threads -> 16B line)
          if (Cf8) Cf8[((size_t)nt * nrows + gr) * 16 + lm] = f1fp8(v * 256.f);
        }
      }
  }
}

// ---------------- fused link predictor (r9 form — frozen) ---------------------
// 128 pairs/block; z fragments in registers; Wat LDS-staged fragment-order.
// r10: global-Wat +24us; r11: 256-pair halves -> 136 VGPR, occ 10%, +28us.
__global__ __launch_bounds__(256) void k_pred(const unsigned short* __restrict__ h,
                                              const int* __restrict__ pairs,
                                              const unsigned short* __restrict__ Wat,  // fragment-ordered [32][64][8]
                                              const float* __restrict__ ba,
                                              const float* __restrict__ Wb,
                                              const float* __restrict__ bb,
                                              float* __restrict__ scores, int P) {
  __shared__ unsigned short wat_sh[128 * 128];  // 32 KB, fragment order
  __shared__ int pa[128], pb[128];
  int t = threadIdx.x;
  int p0 = blockIdx.x * 128;
  {
    const uint4* src = (const uint4*)Wat;
    uint4* dst = (uint4*)wat_sh;
#pragma unroll
    for (int i = 0; i < 8; ++i) dst[t + i * 256] = src[t + i * 256];
  }
  if (t < 128) {
    int p = p0 + t;
    if (p > P - 1) p = P - 1;
    pa[t] = pairs[2 * p];
    pb[t] = pairs[2 * p + 1];
  }
  __syncthreads();
  int w = t >> 6, l = t & 63, quad = l >> 4, lm = l & 15;
  int rowA = w * 32 + lm;
  int rowB = w * 32 + 16 + lm;
  const unsigned short* ha0 = h + (size_t)pa[rowA] * DN + quad * 8;
  const unsigned short* hb0 = h + (size_t)pb[rowA] * DN + quad * 8;
  const unsigned short* ha1 = h + (size_t)pa[rowB] * DN + quad * 8;
  const unsigned short* hb1 = h + (size_t)pb[rowB] * DN + quad * 8;

  uint4 ua0[4], ub0[4], ua1[4], ub1[4];
#pragma unroll
  for (int ch = 0; ch < 4; ++ch) {
    ua0[ch] = *(const uint4*)(ha0 + ch * 32);
    ub0[ch] = *(const uint4*)(hb0 + ch * 32);
    ua1[ch] = *(const uint4*)(ha1 + ch * 32);
    ub1[ch] = *(const uint4*)(hb1 + ch * 32);
  }

  f32x4 acc[2][8];
#pragma unroll
  for (int i = 0; i < 2; ++i)
#pragma unroll
    for (int j = 0; j < 8; ++j) acc[i][j] = (f32x4){0.f, 0.f, 0.f, 0.f};

#pragma unroll
  for (int ch = 0; ch < 4; ++ch) {
    uint4 m0, m1;
    m0.x = pkmul(ua0[ch].x, ub0[ch].x);
    m0.y = pkmul(ua0[ch].y, ub0[ch].y);
    m0.z = pkmul(ua0[ch].z, ub0[ch].z);
    m0.w = pkmul(ua0[ch].w, ub0[ch].w);
    m1.x = pkmul(ua1[ch].x, ub1[ch].x);
    m1.y = pkmul(ua1[ch].y, ub1[ch].y);
    m1.z = pkmul(ua1[ch].z, ub1[ch].z);
    m1.w = pkmul(ua1[ch].w, ub1[ch].w);
    bf16x8 af0 = *(bf16x8*)&m0;
    bf16x8 af1 = *(bf16x8*)&m1;
#pragma unroll
    for (int nt = 0; nt < 8; ++nt) {
      bf16x8 bfr = *(bf16x8*)&wat_sh[(((ch * 8 + nt) * 64) + l) * 8];
      acc[0][nt] = __builtin_amdgcn_mfma_f32_16x16x32_bf16(af0, bfr, acc[0][nt], 0, 0, 0);
      acc[1][nt] = __builtin_amdgcn_mfma_f32_16x16x32_bf16(af1, bfr, acc[1][nt], 0, 0, 0);
    }
  }
  float s[2][4] = {{0.f, 0.f, 0.f, 0.f}, {0.f, 0.f, 0.f, 0.f}};
#pragma unroll
  for (int nt = 0; nt < 8; ++nt) {
    int col = nt * 16 + lm;
    float bav = ba[col];
    float wbv = Wb[col];
#pragma unroll
    for (int mt = 0; mt < 2; ++mt)
#pragma unroll
      for (int r = 0; r < 4; ++r)
        s[mt][r] += fmaxf(acc[mt][nt][r] + bav, 0.f) * wbv;
  }
#pragma unroll
  for (int mask = 1; mask <= 8; mask <<= 1)
#pragma unroll
    for (int mt = 0; mt < 2; ++mt)
#pragma unroll
      for (int r = 0; r < 4; ++r) s[mt][r] += __shfl_xor(s[mt][r], mask);
  if (lm == 0) {
    float bbv = bb[0];
#pragma unroll
    for (int mt = 0; mt < 2; ++mt)
#pragma unroll
      for (int r = 0; r < 4; ++r) {
        int p = p0 + w * 32 + mt * 16 + quad * 4 + r;
        if (p < P) scores[p] = s[mt][r] + bbv;
      }
  }
}

extern "C" void kernel_launch(void* const* d_in, const int* in_sizes, int n_in,
                              void* d_out, int out_size, void* d_ws, size_t ws_size,
                              hipStream_t stream) {
  const int* node_ids = (const int*)d_in[0];
  const int* senders = (const int*)d_in[1];
  const int* receivers = (const int*)d_in[2];
  const int* pairs = (const int*)d_in[3];
  const float* emb = (const float*)d_in[4];
  const float* W1 = (const float*)d_in[5];
  const float* b1 = (const float*)d_in[6];
  const float* W2 = (const float*)d_in[7];
  const float* b2 = (const float*)d_in[8];
  const float* Wa = (const float*)d_in[9];
  const float* ba = (const float*)d_in[10];
  const float* Wb = (const float*)d_in[11];
  const float* bb = (const float*)d_in[12];
  float* scores = (float*)d_out;

  int N = in_sizes[0];
  int E = in_sizes[1];
  int P = in_sizes[3] / 2;
  int NR = (N + RSZ - 1) / RSZ;      // node ranges (196 for N=100k)
  int CE = (E + NCHUNK - 1) / NCHUNK;  // 3125 <= LDSE

  char* w = (char*)d_ws;
  auto alloc = [&](size_t bytes) {
    void* p = (void*)w;
    w += (bytes + 255) & ~(size_t)255;
    return p;
  };
  unsigned short* xb = (unsigned short*)alloc((size_t)N * DN * 2);  // x, later h
  unsigned short* ub = (unsigned short*)alloc((size_t)N * DN * 2);  // aggregated msgs
  unsigned short* y1b = (unsigned short*)alloc((size_t)N * DN * 2); // layer-1 out
  unsigned char* xf8 = (unsigned char*)alloc((size_t)N * DN);      // fp8 slices L1 [8][N][16]
  unsigned char* y1f8 = (unsigned char*)alloc((size_t)N * DN);     // fp8 slices L2 [8][N][16]
  unsigned short* Wt1 = (unsigned short*)alloc(256 * 128 * 2);
  unsigned short* Wt2 = (unsigned short*)alloc(256 * 128 * 2);
  unsigned short* Wat = (unsigned short*)alloc(128 * 128 * 2);
  float* scale_s = (float*)alloc((size_t)N * 4);
  float* scale_r = (float*)alloc((size_t)N * 4);
  int* cnt_r = (int*)alloc((size_t)N * 4);
  int* rbuf = (int*)alloc((size_t)E * 4);                          // dense edge words
  unsigned short* sbuf = (unsigned short*)alloc((size_t)E * 2);    // dense sender locals
  int* rc = (int*)alloc((size_t)NR * NCHUNK * 4);
  int* ro = (int*)alloc((size_t)NR * NCHUNK * 4);
  int* sc = (int*)alloc((size_t)NR * NCHUNK * 4);
  int* so = (int*)alloc((size_t)NR * NCHUNK * 4);
  int* csr = (int*)alloc((size_t)NR * RSZ * SLOTS * 4);

  // weight prep
  k_wt3<<<(81920 + 255) / 256, 256, 0, stream>>>(W1, W2, Wa, Wt1, Wt2, Wat);

  // phase A: LDS-staged routing + emb gather (bf16 + slice-major fp8)
  int gather_blocks = (N * (DN / 4) + 1023) / 1024;
  k_route<<<NCHUNK + gather_blocks, 256, 0, stream>>>(
      senders, receivers, rbuf, sbuf, rc, ro, sc, so, E, CE, NR,
      node_ids, emb, xb, xf8, N);

  // phase B: per-range CSR + degrees + scales
  k_build2<<<NR, 256, 0, stream>>>(rbuf, sbuf, rc, ro, sc, so, cnt_r, csr,
                                   scale_s, scale_r, N, CE);

  int agg_blocks = ((N + 63) / 64) * 8;
  // layer 1 (XCD-pinned K-slice fp8 gather)
  k_aggregate8<<<agg_blocks, 256, 0, stream>>>(xf8, cnt_r, csr, scale_s, scale_r, ub, N);
  k_gemm<<<(N + 127) / 128, 256, 0, stream>>>(xb, ub, Wt1, b1, y1b, y1f8, N, 1);

  // layer 2 (h into xb; x dead) — h stays bf16 for the predictor
  k_aggregate8<<<agg_blocks, 256, 0, stream>>>(y1f8, cnt_r, csr, scale_s, scale_r, ub, N);
  k_gemm<<<(N + 127) / 128, 256, 0, stream>>>(y1b, ub, Wt2, b2, xb, (unsigned char*)0, N, 0);

  // predictor (bf16 pair gather, LDS Wat, 128 pairs/block — r9 frozen form)
  k_pred<<<(P + 127) / 128, 256, 0, stream>>>(xb, pairs, Wat, ba, Wb, bb, scores, P);
}

// Round 13
// 391.431 us; speedup vs baseline: 1.3799x; 1.3799x over previous
//
#include <hip/hip_runtime.h>

#define DN 128
#define SLOTS 64
#define RSZ 512      // nodes per range (power of 2)
#define NCHUNK 512   // edge chunks; dense staged output makes chunk size write-neutral
#define LDSE 3200    // LDS staging capacity >= CE = E/NCHUNK = 3125

typedef __attribute__((ext_vector_type(8))) short bf16x8;
typedef __attribute__((ext_vector_type(4))) float f32x4;
typedef __attribute__((ext_vector_type(2))) float f32x2;

__device__ __forceinline__ unsigned short f2bf(float f) {
  unsigned int b = __float_as_uint(f);
  b += 0x7fffu + ((b >> 16) & 1u);
  return (unsigned short)(b >> 16);
}

__device__ __forceinline__ unsigned int pkmul(unsigned int a, unsigned int b) {
  float a0 = __uint_as_float(a << 16);
  float a1 = __uint_as_float(a & 0xffff0000u);
  float b0 = __uint_as_float(b << 16);
  float b1 = __uint_as_float(b & 0xffff0000u);
  return (unsigned int)f2bf(a0 * b0) | ((unsigned int)f2bf(a1 * b1) << 16);
}

// ---------------- fp8 (OCP e4m3fn) helpers ----------------
// AGGREGATION-ONLY (r7: fp8 pair product absmax 1.55e-6 > 5.8e-7 threshold).
// Row-major 128B fp8 rows are mandatory: r12's 16B-sliced gathers were
// request-rate-bound (8x requests, 2.5x slower despite higher L2 hit rate).
#if __has_builtin(__builtin_amdgcn_cvt_pk_f32_fp8)
template <bool HI>
__device__ __forceinline__ f32x2 fp8pair(unsigned int w) {
  return __builtin_amdgcn_cvt_pk_f32_fp8((int)w, HI);
}
#else
__device__ __forceinline__ float fp8dec1(unsigned int b) {
  float v = __uint_as_float((b & 0x7fu) << 20) * 1.329227996e36f;  // *2^120
  return (b & 0x80u) ? -v : v;
}
template <bool HI>
__device__ __forceinline__ f32x2 fp8pair(unsigned int w) {
  unsigned int s = HI ? (w >> 16) : w;
  f32x2 r;
  r.x = fp8dec1(s & 0xffu);
  r.y = fp8dec1((s >> 8) & 0xffu);
  return r;
}
#endif

#if __has_builtin(__builtin_amdgcn_cvt_pk_fp8_f32)
__device__ __forceinline__ unsigned int f4fp8(float a, float b, float c, float d) {
  int lo = __builtin_amdgcn_cvt_pk_fp8_f32(a, b, 0, false);
  return (unsigned int)__builtin_amdgcn_cvt_pk_fp8_f32(c, d, lo, true);
}
__device__ __forceinline__ unsigned char f1fp8(float v) {
  return (unsigned char)(__builtin_amdgcn_cvt_pk_fp8_f32(v, v, 0, false) & 0xff);
}
#else
__device__ __forceinline__ unsigned char f1fp8(float v) {
  unsigned int sign = (__float_as_uint(v) >> 24) & 0x80u;
  float av = fabsf(v);
  if (av > 448.f) av = 448.f;
  unsigned int byte;
  unsigned int u = __float_as_uint(av);
  if (av < 0.015625f) {  // below min normal 2^-6: subnormal m*2^-9
    int m = (int)(av * 512.0f + 0.5f);
    byte = (unsigned int)m;
  } else {
    u += (1u << 19);
    int ee = (int)(u >> 23) - 127 + 7;
    unsigned int m3 = (u >> 20) & 7;
    if (ee > 15) byte = 0x7eu;
    else byte = ((unsigned int)ee << 3) | m3;
  }
  return (unsigned char)(byte | sign);
}
__device__ __forceinline__ unsigned int f4fp8(float a, float b, float c, float d) {
  return (unsigned int)f1fp8(a) | ((unsigned int)f1fp8(b) << 8) |
         ((unsigned int)f1fp8(c) << 16) | ((unsigned int)f1fp8(d) << 24);
}
#endif

// ---------------- phase A: LDS-staged edge routing + fused emb gather --------
// Two-pass counting sort per chunk -> dense full-line flush (r9: -20us vs
// scattered CAP-padded appends; r5/r6/r8 all showed partial-line thrash).
__global__ __launch_bounds__(256) void k_route(const int* __restrict__ snd,
                                               const int* __restrict__ rcv,
                                               int* __restrict__ rbuf,
                                               unsigned short* __restrict__ sbuf,
                                               int* __restrict__ rc, int* __restrict__ ro,
                                               int* __restrict__ sc, int* __restrict__ so,
                                               int E, int CE, int NR,
                                               const int* __restrict__ node_ids,
                                               const float* __restrict__ emb,
                                               unsigned short* __restrict__ x,
                                               unsigned char* __restrict__ xf8, int n) {
  if ((int)blockIdx.x < NCHUNK) {
    __shared__ int cR[256], cS[256], curR[256], curS[256];
    __shared__ int rdata[LDSE];
    __shared__ unsigned short sdata[LDSE];
    int t = threadIdx.x;
    int chunk = blockIdx.x;
    cR[t] = 0;
    cS[t] = 0;
    __syncthreads();
    int e0 = chunk * CE;
    int e1 = e0 + CE;
    if (e1 > E) e1 = E;
    // pass 1: per-range counts (snd/rcv stay L2-hot for pass 2)
    for (int e = e0 + t; e < e1; e += 256) {
      atomicAdd(&cR[rcv[e] >> 9], 1);
      atomicAdd(&cS[snd[e] >> 9], 1);
    }
    __syncthreads();
    // inclusive Hillis-Steele scan -> exclusive cursors
    curR[t] = cR[t];
    curS[t] = cS[t];
    __syncthreads();
#pragma unroll
    for (int off = 1; off < 256; off <<= 1) {
      int aR = (t >= off) ? curR[t - off] : 0;
      int aS = (t >= off) ? curS[t - off] : 0;
      __syncthreads();
      curR[t] += aR;
      curS[t] += aS;
      __syncthreads();
    }
    curR[t] -= cR[t];  // own element only: no cross-thread hazard
    curS[t] -= cS[t];
    __syncthreads();
    // pass 2: scatter into dense LDS staging
    for (int e = e0 + t; e < e1; e += 256) {
      int s = snd[e], r = rcv[e];
      int pos = atomicAdd(&curR[r >> 9], 1);
      rdata[pos] = ((r & (RSZ - 1)) << 17) | s;
      int pos2 = atomicAdd(&curS[s >> 9], 1);
      sdata[pos2] = (unsigned short)(s & (RSZ - 1));
    }
    __syncthreads();
    // flush: dense, coalesced, full-line writes
    int cnt = e1 - e0;
    for (int i = t; i < cnt; i += 256) rbuf[(size_t)chunk * CE + i] = rdata[i];
    for (int i = t; i < cnt; i += 256) sbuf[(size_t)chunk * CE + i] = sdata[i];
    if (t < NR) {
      rc[t * NCHUNK + chunk] = cR[t];
      ro[t * NCHUNK + chunk] = curR[t] - cR[t];  // cursor advanced by exactly cR[t]
      sc[t * NCHUNK + chunk] = cS[t];
      so[t * NCHUNK + chunk] = curS[t] - cS[t];
    }
  } else {
    int gblk = blockIdx.x - NCHUNK;
    int total = n * (DN / 4);
#pragma unroll
    for (int kk = 0; kk < 4; ++kk) {
      int idx = gblk * 1024 + kk * 256 + threadIdx.x;
      if (idx >= total) continue;
      int row = idx >> 5;
      int c4 = (idx & 31) << 2;
      int src = node_ids[row];
      float4 v = *(const float4*)(emb + (size_t)src * DN + c4);
      uint2 o;
      o.x = (unsigned int)f2bf(v.x) | ((unsigned int)f2bf(v.y) << 16);
      o.y = (unsigned int)f2bf(v.z) | ((unsigned int)f2bf(v.w) << 16);
      *(uint2*)(x + (size_t)row * DN + c4) = o;
      *(unsigned int*)(xf8 + (size_t)row * DN + c4) =
          f4fp8(v.x * 256.f, v.y * 256.f, v.z * 256.f, v.w * 256.f);
    }
  }
}

// ---------------- phase B: per-range CSR in LDS + degrees + scales ------------
// csr block [512][64] built in LDS (128KB; NR=196 blocks < 256 CUs so 1
// block/CU residency is unchanged), then flushed as dense full lines —
// same partial-line-writeback fix that saved k_route 20us (r9). Unfilled
// slots flush garbage; the aggregate reads only j < cnt_r.
__global__ __launch_bounds__(256) void k_build2(const int* __restrict__ rbuf,
                                                const unsigned short* __restrict__ sbuf,
                                                const int* __restrict__ rc,
                                                const int* __restrict__ ro,
                                                const int* __restrict__ sc,
                                                const int* __restrict__ so,
                                                int* __restrict__ cnt_r,
                                                int* __restrict__ csr,
                                                float* __restrict__ scale_s,
                                                float* __restrict__ scale_r,
                                                int N, int CE) {
  __shared__ int cur[RSZ], hist[RSZ];
  __shared__ int csr_sh[RSZ * SLOTS];  // 128 KB
  int g = blockIdx.x, t = threadIdx.x;
  cur[t] = 0;
  cur[t + 256] = 0;
  hist[t] = 0;
  hist[t + 256] = 0;
  __syncthreads();
#pragma unroll
  for (int cc = 0; cc < 2; ++cc) {
    int chunk = t + cc * 256;
    int cnt = rc[g * NCHUNK + chunk];
    const int* row = rbuf + (size_t)chunk * CE + ro[g * NCHUNK + chunk];
    for (int i = 0; i < cnt; ++i) {
      int e = row[i];
      int rl = e >> 17;
      int s = e & 0x1FFFF;
      int sl = atomicAdd(&cur[rl], 1);
      if (sl < SLOTS) csr_sh[rl * SLOTS + sl] = s;
    }
    int cnt2 = sc[g * NCHUNK + chunk];
    const unsigned short* row2 = sbuf + (size_t)chunk * CE + so[g * NCHUNK + chunk];
    for (int i = 0; i < cnt2; ++i) atomicAdd(&hist[row2[i]], 1);
  }
  __syncthreads();
#pragma unroll
  for (int k = 0; k < 2; ++k) {
    int tt = t + k * 256;
    int node = g * RSZ + tt;
    if (node < N) {
      int c = cur[tt];
      cnt_r[node] = c;
      float cr = (float)(c + 1);
      scale_r[node] = 1.0f / (cr * sqrtf(cr));
      float ds = (float)(hist[tt] + 1);
      scale_s[node] = 1.0f / sqrtf(ds);
    }
  }
  // dense coalesced flush of the whole range's CSR block (full lines only)
  {
    int4* dst = (int4*)(csr + (size_t)g * RSZ * SLOTS);
    const int4* src4 = (const int4*)csr_sh;
    for (int i = t; i < RSZ * SLOTS / 4; i += 256) dst[i] = src4[i];
  }
}

// ---------------- weight transpose+convert (all three weights) ----------------
// Wat is emitted in MFMA B-fragment order for k_pred's conflict-free LDS reads.
// (r10: reading Wat from global costs +24us — it must be LDS-staged.)
__global__ __launch_bounds__(256) void k_wt3(const float* __restrict__ W1,
                                             const float* __restrict__ W2,
                                             const float* __restrict__ Wa,
                                             unsigned short* __restrict__ Wt1,
                                             unsigned short* __restrict__ Wt2,
                                             unsigned short* __restrict__ Wat) {
  int idx = blockIdx.x * 256 + threadIdx.x;
  if (idx < 32768) {
    int k = idx >> 7, n = idx & 127;
    Wt1[n * 256 + k] = f2bf(W1[idx]);
  } else if (idx < 65536) {
    int i = idx - 32768;
    int k = i >> 7, n = i & 127;
    Wt2[n * 256 + k] = f2bf(W2[i]);
  } else if (idx < 81920) {
    int i = idx - 65536;
    int k = i >> 7, n = i & 127;
    int ch = k >> 5, quad = (k >> 3) & 3, j = k & 7;
    int nt = n >> 4, lm = n & 15;
    int pos = (((ch * 8 + nt) * 64) + quad * 16 + lm) * 8 + j;
    Wat[pos] = f2bf(Wa[i]);
  }
}

// ---------------- per-node gather aggregation (fp8 in, bf16 out, fp32 accum) ---
// Rows are fp8 e4m3 of (value * 256); the 2^-8 is folded into the final scale.
// 32 lanes/node = one 128B request per edge — the request-rate-optimal shape.
__device__ __forceinline__ void acc8(unsigned int u, float wgt, float& ax, float& ay,
                                     float& az, float& aw) {
  f32x2 lo = fp8pair<false>(u);
  f32x2 hi = fp8pair<true>(u);
  ax += lo.x * wgt;
  ay += lo.y * wgt;
  az += hi.x * wgt;
  aw += hi.y * wgt;
}

__global__ __launch_bounds__(256) void k_aggregate8(const unsigned char* __restrict__ xf8,
                                                    const int* __restrict__ cnt_r,
                                                    const int* __restrict__ csr,
                                                    const float* __restrict__ scale_s,
                                                    const float* __restrict__ scale_r,
                                                    unsigned short* __restrict__ out, int n) {
  int hw = threadIdx.x >> 5;
  int lane = threadIdx.x & 31;
  int node = blockIdx.x * 8 + hw;
  if (node >= n) return;
  int start = node * SLOTS;
  int cnt = cnt_r[node];
  if (cnt > SLOTS) cnt = SLOTS;
  int c = lane * 4;  // 4 dims = 4 bytes
  float ws = scale_s[node];
  float ax = 0.f, ay = 0.f, az = 0.f, aw = 0.f;
  acc8(*(const unsigned int*)(xf8 + (size_t)node * DN + c), ws, ax, ay, az, aw);  // self
  int j = 0;
  for (; j + 8 <= cnt; j += 8) {
    int4 ea = *(const int4*)(csr + start + j);
    int4 eb = *(const int4*)(csr + start + j + 4);
    float w0 = scale_s[ea.x], w1 = scale_s[ea.y], w2 = scale_s[ea.z], w3 = scale_s[ea.w];
    float w4 = scale_s[eb.x], w5 = scale_s[eb.y], w6 = scale_s[eb.z], w7 = scale_s[eb.w];
    unsigned int u0 = *(const unsigned int*)(xf8 + (size_t)ea.x * DN + c);
    unsigned int u1 = *(const unsigned int*)(xf8 + (size_t)ea.y * DN + c);
    unsigned int u2 = *(const unsigned int*)(xf8 + (size_t)ea.z * DN + c);
    unsigned int u3 = *(const unsigned int*)(xf8 + (size_t)ea.w * DN + c);
    unsigned int u4 = *(const unsigned int*)(xf8 + (size_t)eb.x * DN + c);
    unsigned int u5 = *(const unsigned int*)(xf8 + (size_t)eb.y * DN + c);
    unsigned int u6 = *(const unsigned int*)(xf8 + (size_t)eb.z * DN + c);
    unsigned int u7 = *(const unsigned int*)(xf8 + (size_t)eb.w * DN + c);
    acc8(u0, w0, ax, ay, az, aw);
    acc8(u1, w1, ax, ay, az, aw);
    acc8(u2, w2, ax, ay, az, aw);
    acc8(u3, w3, ax, ay, az, aw);
    acc8(u4, w4, ax, ay, az, aw);
    acc8(u5, w5, ax, ay, az, aw);
    acc8(u6, w6, ax, ay, az, aw);
    acc8(u7, w7, ax, ay, az, aw);
  }
  for (; j + 4 <= cnt; j += 4) {
    int4 ea = *(const int4*)(csr + start + j);
    float w0 = scale_s[ea.x], w1 = scale_s[ea.y], w2 = scale_s[ea.z], w3 = scale_s[ea.w];
    unsigned int u0 = *(const unsigned int*)(xf8 + (size_t)ea.x * DN + c);
    unsigned int u1 = *(const unsigned int*)(xf8 + (size_t)ea.y * DN + c);
    unsigned int u2 = *(const unsigned int*)(xf8 + (size_t)ea.z * DN + c);
    unsigned int u3 = *(const unsigned int*)(xf8 + (size_t)ea.w * DN + c);
    acc8(u0, w0, ax, ay, az, aw);
    acc8(u1, w1, ax, ay, az, aw);
    acc8(u2, w2, ax, ay, az, aw);
    acc8(u3, w3, ax, ay, az, aw);
  }
  for (; j < cnt; ++j) {
    int s0 = csr[start + j];
    float w0 = scale_s[s0];
    unsigned int u0 = *(const unsigned int*)(xf8 + (size_t)s0 * DN + c);
    acc8(u0, w0, ax, ay, az, aw);
  }
  float sr = scale_r[node] * 0.00390625f;  // fold 2^-8 dequant scale
  uint2 o;
  o.x = (unsigned int)f2bf(ax * sr) | ((unsigned int)f2bf(ay * sr) << 16);
  o.y = (unsigned int)f2bf(az * sr) | ((unsigned int)f2bf(aw * sr) << 16);
  *(uint2*)(out + (size_t)node * DN + c) = o;
}

// ---------------- layer GEMM (MFMA bf16): C = relu?( [A1|A2] @ W + bias ) -------
// C (bf16) and Cf8 (fp8 of C*256, row-major) are each optional outputs.
__global__ __launch_bounds__(256) void k_gemm(const unsigned short* __restrict__ A1,
                                              const unsigned short* __restrict__ A2,
                                              const unsigned short* __restrict__ Wt,  // [128][256] bf16
                                              const float* __restrict__ bias,
                                              unsigned short* __restrict__ C,
                                              unsigned char* __restrict__ Cf8,
                                              int nrows, int dorelu) {
  __shared__ unsigned short a_sh[128 * 40];  // [row][k], stride 40 (pad)
  __shared__ unsigned short b_sh[128 * 40];  // [n][k], stride 40
  int t = threadIdx.x;
  int w = t >> 6, l = t & 63, quad = l >> 4, lm = l & 15;
  int row0 = blockIdx.x * 128;
  f32x4 acc[2][8];
#pragma unroll
  for (int i = 0; i < 2; ++i)
#pragma unroll
    for (int j = 0; j < 8; ++j) acc[i][j] = (f32x4){0.f, 0.f, 0.f, 0.f};

  for (int ch = 0; ch < 8; ++ch) {
    const unsigned short* src = (ch < 4) ? A1 : A2;
    int kb = (ch & 3) * 32;
    int kk = ch * 32;
#pragma unroll
    for (int rep = 0; rep < 2; ++rep) {
      int idx = t + rep * 256;
      int r = idx >> 2, q = idx & 3;
      int gr = row0 + r;
      if (gr > nrows - 1) gr = nrows - 1;
      *(uint4*)&a_sh[r * 40 + q * 8] = *(const uint4*)(src + (size_t)gr * DN + kb + q * 8);
      int nn = idx >> 2;
      *(uint4*)&b_sh[nn * 40 + q * 8] = *(const uint4*)(Wt + (size_t)nn * 256 + kk + q * 8);
    }
    __syncthreads();
    bf16x8 af0 = *(bf16x8*)&a_sh[(w * 32 + lm) * 40 + quad * 8];
    bf16x8 af1 = *(bf16x8*)&a_sh[(w * 32 + 16 + lm) * 40 + quad * 8];
#pragma unroll
    for (int nt = 0; nt < 8; ++nt) {
      bf16x8 bfr = *(bf16x8*)&b_sh[(nt * 16 + lm) * 40 + quad * 8];
      acc[0][nt] = __builtin_amdgcn_mfma_f32_16x16x32_bf16(af0, bfr, acc[0][nt], 0, 0, 0);
      acc[1][nt] = __builtin_amdgcn_mfma_f32_16x16x32_bf16(af1, bfr, acc[1][nt], 0, 0, 0);
    }
    __syncthreads();
  }
#pragma unroll
  for (int nt = 0; nt < 8; ++nt) {
    int col = nt * 16 + lm;
    float bv = bias[col];
#pragma unroll
    for (int mt = 0; mt < 2; ++mt)
#pragma unroll
      for (int r = 0; r < 4; ++r) {
        int gr = row0 + w * 32 + mt * 16 + quad * 4 + r;
        if (gr < nrows) {
          float v = acc[mt][nt][r] + bv;
          if (dorelu) v = fmaxf(v, 0.f);
          if (C) C[(size_t)gr * DN + col] = f2bf(v);
          if (Cf8) Cf8[(size_t)gr * DN + col] = f1fp8(v * 256.f);
        }
      }
  }
}

// ---------------- fused link predictor (r9 form — frozen) ---------------------
// 128 pairs/block; z fragments in registers; Wat LDS-staged fragment-order.
// r10: global-Wat +24us; r11: 256-pair halves -> 136 VGPR, occ 10%, +28us.
__global__ __launch_bounds__(256) void k_pred(const unsigned short* __restrict__ h,
                                              const int* __restrict__ pairs,
                                              const unsigned short* __restrict__ Wat,  // fragment-ordered [32][64][8]
                                              const float* __restrict__ ba,
                                              const float* __restrict__ Wb,
                                              const float* __restrict__ bb,
                                              float* __restrict__ scores, int P) {
  __shared__ unsigned short wat_sh[128 * 128];  // 32 KB, fragment order
  __shared__ int pa[128], pb[128];
  int t = threadIdx.x;
  int p0 = blockIdx.x * 128;
  {
    const uint4* src = (const uint4*)Wat;
    uint4* dst = (uint4*)wat_sh;
#pragma unroll
    for (int i = 0; i < 8; ++i) dst[t + i * 256] = src[t + i * 256];
  }
  if (t < 128) {
    int p = p0 + t;
    if (p > P - 1) p = P - 1;
    pa[t] = pairs[2 * p];
    pb[t] = pairs[2 * p + 1];
  }
  __syncthreads();
  int w = t >> 6, l = t & 63, quad = l >> 4, lm = l & 15;
  int rowA = w * 32 + lm;
  int rowB = w * 32 + 16 + lm;
  const unsigned short* ha0 = h + (size_t)pa[rowA] * DN + quad * 8;
  const unsigned short* hb0 = h + (size_t)pb[rowA] * DN + quad * 8;
  const unsigned short* ha1 = h + (size_t)pa[rowB] * DN + quad * 8;
  const unsigned short* hb1 = h + (size_t)pb[rowB] * DN + quad * 8;

  uint4 ua0[4], ub0[4], ua1[4], ub1[4];
#pragma unroll
  for (int ch = 0; ch < 4; ++ch) {
    ua0[ch] = *(const uint4*)(ha0 + ch * 32);
    ub0[ch] = *(const uint4*)(hb0 + ch * 32);
    ua1[ch] = *(const uint4*)(ha1 + ch * 32);
    ub1[ch] = *(const uint4*)(hb1 + ch * 32);
  }

  f32x4 acc[2][8];
#pragma unroll
  for (int i = 0; i < 2; ++i)
#pragma unroll
    for (int j = 0; j < 8; ++j) acc[i][j] = (f32x4){0.f, 0.f, 0.f, 0.f};

#pragma unroll
  for (int ch = 0; ch < 4; ++ch) {
    uint4 m0, m1;
    m0.x = pkmul(ua0[ch].x, ub0[ch].x);
    m0.y = pkmul(ua0[ch].y, ub0[ch].y);
    m0.z = pkmul(ua0[ch].z, ub0[ch].z);
    m0.w = pkmul(ua0[ch].w, ub0[ch].w);
    m1.x = pkmul(ua1[ch].x, ub1[ch].x);
    m1.y = pkmul(ua1[ch].y, ub1[ch].y);
    m1.z = pkmul(ua1[ch].z, ub1[ch].z);
    m1.w = pkmul(ua1[ch].w, ub1[ch].w);
    bf16x8 af0 = *(bf16x8*)&m0;
    bf16x8 af1 = *(bf16x8*)&m1;
#pragma unroll
    for (int nt = 0; nt < 8; ++nt) {
      bf16x8 bfr = *(bf16x8*)&wat_sh[(((ch * 8 + nt) * 64) + l) * 8];
      acc[0][nt] = __builtin_amdgcn_mfma_f32_16x16x32_bf16(af0, bfr, acc[0][nt], 0, 0, 0);
      acc[1][nt] = __builtin_amdgcn_mfma_f32_16x16x32_bf16(af1, bfr, acc[1][nt], 0, 0, 0);
    }
  }
  float s[2][4] = {{0.f, 0.f, 0.f, 0.f}, {0.f, 0.f, 0.f, 0.f}};
#pragma unroll
  for (int nt = 0; nt < 8; ++nt) {
    int col = nt * 16 + lm;
    float bav = ba[col];
    float wbv = Wb[col];
#pragma unroll
    for (int mt = 0; mt < 2; ++mt)
#pragma unroll
      for (int r = 0; r < 4; ++r)
        s[mt][r] += fmaxf(acc[mt][nt][r] + bav, 0.f) * wbv;
  }
#pragma unroll
  for (int mask = 1; mask <= 8; mask <<= 1)
#pragma unroll
    for (int mt = 0; mt < 2; ++mt)
#pragma unroll
      for (int r = 0; r < 4; ++r) s[mt][r] += __shfl_xor(s[mt][r], mask);
  if (lm == 0) {
    float bbv = bb[0];
#pragma unroll
    for (int mt = 0; mt < 2; ++mt)
#pragma unroll
      for (int r = 0; r < 4; ++r) {
        int p = p0 + w * 32 + mt * 16 + quad * 4 + r;
        if (p < P) scores[p] = s[mt][r] + bbv;
      }
  }
}

extern "C" void kernel_launch(void* const* d_in, const int* in_sizes, int n_in,
                              void* d_out, int out_size, void* d_ws, size_t ws_size,
                              hipStream_t stream) {
  const int* node_ids = (const int*)d_in[0];
  const int* senders = (const int*)d_in[1];
  const int* receivers = (const int*)d_in[2];
  const int* pairs = (const int*)d_in[3];
  const float* emb = (const float*)d_in[4];
  const float* W1 = (const float*)d_in[5];
  const float* b1 = (const float*)d_in[6];
  const float* W2 = (const float*)d_in[7];
  const float* b2 = (const float*)d_in[8];
  const float* Wa = (const float*)d_in[9];
  const float* ba = (const float*)d_in[10];
  const float* Wb = (const float*)d_in[11];
  const float* bb = (const float*)d_in[12];
  float* scores = (float*)d_out;

  int N = in_sizes[0];
  int E = in_sizes[1];
  int P = in_sizes[3] / 2;
  int NR = (N + RSZ - 1) / RSZ;      // node ranges (196 for N=100k)
  int CE = (E + NCHUNK - 1) / NCHUNK;  // 3125 <= LDSE

  char* w = (char*)d_ws;
  auto alloc = [&](size_t bytes) {
    void* p = (void*)w;
    w += (bytes + 255) & ~(size_t)255;
    return p;
  };
  unsigned short* xb = (unsigned short*)alloc((size_t)N * DN * 2);  // x, later h
  unsigned short* ub = (unsigned short*)alloc((size_t)N * DN * 2);  // aggregated msgs
  unsigned short* y1b = (unsigned short*)alloc((size_t)N * DN * 2); // layer-1 out
  unsigned char* xf8 = (unsigned char*)alloc((size_t)N * DN);      // fp8 gather payload L1
  unsigned char* y1f8 = (unsigned char*)alloc((size_t)N * DN);     // fp8 gather payload L2
  unsigned short* Wt1 = (unsigned short*)alloc(256 * 128 * 2);
  unsigned short* Wt2 = (unsigned short*)alloc(256 * 128 * 2);
  unsigned short* Wat = (unsigned short*)alloc(128 * 128 * 2);
  float* scale_s = (float*)alloc((size_t)N * 4);
  float* scale_r = (float*)alloc((size_t)N * 4);
  int* cnt_r = (int*)alloc((size_t)N * 4);
  int* rbuf = (int*)alloc((size_t)E * 4);                          // dense edge words
  unsigned short* sbuf = (unsigned short*)alloc((size_t)E * 2);    // dense sender locals
  int* rc = (int*)alloc((size_t)NR * NCHUNK * 4);
  int* ro = (int*)alloc((size_t)NR * NCHUNK * 4);
  int* sc = (int*)alloc((size_t)NR * NCHUNK * 4);
  int* so = (int*)alloc((size_t)NR * NCHUNK * 4);
  int* csr = (int*)alloc((size_t)NR * RSZ * SLOTS * 4);

  // weight prep
  k_wt3<<<(81920 + 255) / 256, 256, 0, stream>>>(W1, W2, Wa, Wt1, Wt2, Wat);

  // phase A: LDS-staged routing + emb gather (bf16 + fp8)
  int gather_blocks = (N * (DN / 4) + 1023) / 1024;
  k_route<<<NCHUNK + gather_blocks, 256, 0, stream>>>(
      senders, receivers, rbuf, sbuf, rc, ro, sc, so, E, CE, NR,
      node_ids, emb, xb, xf8, N);

  // phase B: per-range CSR (LDS-staged, dense flush) + degrees + scales
  k_build2<<<NR, 256, 0, stream>>>(rbuf, sbuf, rc, ro, sc, so, cnt_r, csr,
                                   scale_s, scale_r, N, CE);

  // layer 1 (fp8 gather)
  k_aggregate8<<<(N + 7) / 8, 256, 0, stream>>>(xf8, cnt_r, csr, scale_s, scale_r, ub, N);
  k_gemm<<<(N + 127) / 128, 256, 0, stream>>>(xb, ub, Wt1, b1, y1b, y1f8, N, 1);

  // layer 2 (h into xb; x dead) — h stays bf16 for the predictor
  k_aggregate8<<<(N + 7) / 8, 256, 0, stream>>>(y1f8, cnt_r, csr, scale_s, scale_r, ub, N);
  k_gemm<<<(N + 127) / 128, 256, 0, stream>>>(y1b, ub, Wt2, b2, xb, (unsigned char*)0, N, 0);

  // predictor (bf16 pair gather, LDS Wat, 128 pairs/block — r9 frozen form)
  k_pred<<<(P + 127) / 128, 256, 0, stream>>>(xb, pairs, Wat, ba, Wb, bb, scores, P);
}